// Round 7
// baseline (175.889 us; speedup 1.0000x reference)
//
#include <hip/hip_runtime.h>

#define N_VOX  150000
#define KNBR   27
#define CIN    32
#define COUT   64
#define NBUCKET 64
#define NEG_SLOPE 0.01f
#define EPS 1e-5f
#define APPLY_BLOCKS 1024
#define VPB 256            // voxels per conv block (64 per wave)

typedef __bf16 bf16x8 __attribute__((ext_vector_type(8)));
typedef float  f32x4  __attribute__((ext_vector_type(4)));

// fused-prep block ranges
#define NB_FEATS 2344   // ceil(N*CIN/8 / 256)
#define NB_W       27   // K*4*64 / 256
#define NB_Z       32   // NBUCKET*2*COUT / 256

// ===========================================================================
// Prep: feats->bf16, W->B-frag bf16, bsums zero. One launch. (R5-verified)
// ===========================================================================
__global__ __launch_bounds__(256) void prep_all(
    const float* __restrict__ feats, const float* __restrict__ W,
    __bf16* __restrict__ fb, __bf16* __restrict__ Wp,
    float* __restrict__ bsums)
{
    const int t = threadIdx.x;
    int b = blockIdx.x;

    if (b < NB_FEATS) {                       // feats f32 -> bf16
        const int i = b * 256 + t;
        if (i < N_VOX * CIN / 8) {
            const float4* p = reinterpret_cast<const float4*>(feats) + (size_t)i * 2;
            const float4 a = p[0], c = p[1];
            bf16x8 o;
            o[0]=(__bf16)a.x; o[1]=(__bf16)a.y; o[2]=(__bf16)a.z; o[3]=(__bf16)a.w;
            o[4]=(__bf16)c.x; o[5]=(__bf16)c.y; o[6]=(__bf16)c.z; o[7]=(__bf16)c.w;
            reinterpret_cast<bf16x8*>(fb)[i] = o;
        }
        return;
    }
    b -= NB_FEATS;

    if (b < NB_W) {                           // W -> B-fragment order bf16
        const int u = b * 256 + t;            // < 6912
        const int lane = u & 63, f = u >> 6;
        const int s = f & 3, k = f >> 2;
        const int n = lane & 15, q = lane >> 4;
        const float* src = W + ((size_t)(k * CIN + q * 8) * COUT + s * 16 + n);
        bf16x8 o;
#pragma unroll
        for (int j = 0; j < 8; ++j) o[j] = (__bf16)src[(size_t)j * COUT];
        reinterpret_cast<bf16x8*>(Wp)[u] = o;
        return;
    }
    b -= NB_W;

    const int z = b * 256 + t;                // zero bsums
    if (z < NBUCKET * 2 * COUT) bsums[z] = 0.0f;
}

// ===========================================================================
// conv v5: explicit software pipeline.
//   A-gather ring depth 3 (stage k+3 after MFMAs of k)
//   B-frag  ring depth 2 (stage k+1 before MFMAs of k)
// Full unroll over 27 taps -> ring indices are compile-time, pure SSA regs.
// 256 voxels/block, 64/wave; idx staged in LDS (conflict-free, verified).
// ===========================================================================
__global__ __launch_bounds__(256, 2) void conv_mfma5(
    const __bf16* __restrict__ fb,            // [N, CIN] bf16
    const __bf16* __restrict__ Wp,            // prepacked B-frags
    const int* __restrict__ nbr,              // [N, K]
    const int* __restrict__ mask,             // [N, K] int32 bool
    float* __restrict__ out,                  // [N, COUT]
    float* __restrict__ bsums)                // [NBUCKET][2*COUT]
{
    __shared__ int idx_s[VPB * KNBR];         // 27,648 B

    const int t    = threadIdx.x;
    const int base = blockIdx.x * VPB;

    // ---- cooperative masked-idx fill (coalesced) ----
    {
        const size_t gb = (size_t)base * KNBR;
        const int vlim  = N_VOX - base;
        const int ilim  = (vlim < VPB ? vlim : VPB) * KNBR;
#pragma unroll
        for (int j = 0; j < KNBR; ++j) {
            const int i = t + 256 * j;
            int v = -1;
            if (i < ilim) v = (mask[gb + i] != 0) ? nbr[gb + i] : -1;
            idx_s[i] = v;
        }
    }
    __syncthreads();

    const int wave = t >> 6;
    const int lane = t & 63;
    const int n16  = lane & 15;
    const int q    = lane >> 4;
    const int wb   = wave * 64;

    const bf16x8* __restrict__ bp = reinterpret_cast<const bf16x8*>(Wp);
    const bf16x8 zv = {};

    const int rr0 = (wb +  0 + n16) * KNBR;
    const int rr1 = (wb + 16 + n16) * KNBR;
    const int rr2 = (wb + 32 + n16) * KNBR;
    const int rr3 = (wb + 48 + n16) * KNBR;

    f32x4 acc[4][4];                          // [slice][col-subtile]
#pragma unroll
    for (int a = 0; a < 4; ++a)
#pragma unroll
        for (int b2 = 0; b2 < 4; ++b2) acc[a][b2] = (f32x4){0.f,0.f,0.f,0.f};

    bf16x8 ga[3][4];                          // A-gather ring
    bf16x8 bb[2][4];                          // B-frag ring

#define STAGE_A(K, B) do { \
    const int _i0 = idx_s[rr0 + (K)]; \
    const int _i1 = idx_s[rr1 + (K)]; \
    const int _i2 = idx_s[rr2 + (K)]; \
    const int _i3 = idx_s[rr3 + (K)]; \
    ga[B][0] = *reinterpret_cast<const bf16x8*>(fb + (size_t)(_i0 < 0 ? 0 : _i0) * CIN + q * 8); \
    ga[B][1] = *reinterpret_cast<const bf16x8*>(fb + (size_t)(_i1 < 0 ? 0 : _i1) * CIN + q * 8); \
    ga[B][2] = *reinterpret_cast<const bf16x8*>(fb + (size_t)(_i2 < 0 ? 0 : _i2) * CIN + q * 8); \
    ga[B][3] = *reinterpret_cast<const bf16x8*>(fb + (size_t)(_i3 < 0 ? 0 : _i3) * CIN + q * 8); \
    if (_i0 < 0) ga[B][0] = zv; \
    if (_i1 < 0) ga[B][1] = zv; \
    if (_i2 < 0) ga[B][2] = zv; \
    if (_i3 < 0) ga[B][3] = zv; \
} while (0)

#define STAGE_B(K, B) do { \
    bb[B][0] = bp[((K) * 4 + 0) * 64 + lane]; \
    bb[B][1] = bp[((K) * 4 + 1) * 64 + lane]; \
    bb[B][2] = bp[((K) * 4 + 2) * 64 + lane]; \
    bb[B][3] = bp[((K) * 4 + 3) * 64 + lane]; \
} while (0)

    // prologue: A for taps 0,1,2 in flight; B for tap 0
    STAGE_A(0, 0);
    STAGE_B(0, 0);
    STAGE_A(1, 1);
    STAGE_A(2, 2);

#pragma unroll
    for (int k = 0; k < KNBR; ++k) {
        const int cb = k % 3;
        const int db = k & 1;
        if (k + 1 < KNBR) STAGE_B(k + 1, (k + 1) & 1);   // B prefetch 1 ahead
#pragma unroll
        for (int s = 0; s < 4; ++s) {
            acc[0][s] = __builtin_amdgcn_mfma_f32_16x16x32_bf16(ga[cb][0], bb[db][s], acc[0][s], 0, 0, 0);
            acc[1][s] = __builtin_amdgcn_mfma_f32_16x16x32_bf16(ga[cb][1], bb[db][s], acc[1][s], 0, 0, 0);
            acc[2][s] = __builtin_amdgcn_mfma_f32_16x16x32_bf16(ga[cb][2], bb[db][s], acc[2][s], 0, 0, 0);
            acc[3][s] = __builtin_amdgcn_mfma_f32_16x16x32_bf16(ga[cb][3], bb[db][s], acc[3][s], 0, 0, 0);
        }
        if (k + 3 < KNBR) STAGE_A(k + 3, cb);            // A prefetch 3 ahead
    }
#undef STAGE_A
#undef STAGE_B

    // ---- store: C/D layout col=lane&15, row=quad*4+reg (m89-verified) ----
#pragma unroll
    for (int sl = 0; sl < 4; ++sl) {
        const int orow_b = base + wb + sl * 16 + q * 4;
#pragma unroll
        for (int r = 0; r < 4; ++r) {
            const int orow = orow_b + r;
            if (orow < N_VOX) {
                float* dst = out + (size_t)orow * COUT + n16;
#pragma unroll
                for (int s = 0; s < 4; ++s) dst[s * 16] = acc[sl][s][r];
            }
        }
    }

    // ---- per-channel stats: sum slices in-reg, shuffle quads, atomics ----
    float* dstb = bsums + ((blockIdx.x * 4 + wave) & (NBUCKET - 1)) * (2 * COUT);
#pragma unroll
    for (int s = 0; s < 4; ++s) {
        float ps = 0.f, pq = 0.f;
#pragma unroll
        for (int sl = 0; sl < 4; ++sl)
#pragma unroll
            for (int r = 0; r < 4; ++r) {
                const float x = acc[sl][s][r];
                ps += x; pq += x * x;
            }
        ps += __shfl_down(ps, 32); ps += __shfl_down(ps, 16);
        pq += __shfl_down(pq, 32); pq += __shfl_down(pq, 16);
        if (q == 0) {
            atomicAdd(dstb + s * 16 + n16, ps);
            atomicAdd(dstb + COUT + s * 16 + n16, pq);
        }
    }
}

// ===========================================================================
// Fused stats-fold + BN apply + LeakyReLU (R5-verified)
// ===========================================================================
__global__ __launch_bounds__(256) void bn_stats_apply(
    float* __restrict__ out, const float* __restrict__ bsums,
    const float* __restrict__ gamma, const float* __restrict__ beta)
{
    __shared__ float s_sc[COUT], s_sh[COUT];
    const int t = threadIdx.x;
    if (t < COUT) {
        float s = 0.f, qq = 0.f;
#pragma unroll 8
        for (int b = 0; b < NBUCKET; ++b) {
            s  += bsums[b * (2 * COUT) + t];
            qq += bsums[b * (2 * COUT) + COUT + t];
        }
        const float inv_n = 1.0f / (float)N_VOX;
        const float mean  = s * inv_n;
        const float var   = qq * inv_n - mean * mean;
        const float scale = gamma[t] * rsqrtf(var + EPS);
        s_sc[t] = scale;
        s_sh[t] = beta[t] - mean * scale;
    }
    __syncthreads();

    const long total4 = (long)N_VOX * COUT / 4;
    const long stride = (long)APPLY_BLOCKS * 256;
    long i = (long)blockIdx.x * 256 + t;
    const int cg = (int)(i & 15);
    const float4 sc = reinterpret_cast<const float4*>(s_sc)[cg];
    const float4 sh = reinterpret_cast<const float4*>(s_sh)[cg];
    for (; i < total4; i += stride) {
        float4 v = reinterpret_cast<float4*>(out)[i];
        float x;
        x = fmaf(v.x, sc.x, sh.x); v.x = (x >= 0.f) ? x : NEG_SLOPE * x;
        x = fmaf(v.y, sc.y, sh.y); v.y = (x >= 0.f) ? x : NEG_SLOPE * x;
        x = fmaf(v.z, sc.z, sh.z); v.z = (x >= 0.f) ? x : NEG_SLOPE * x;
        x = fmaf(v.w, sc.w, sh.w); v.w = (x >= 0.f) ? x : NEG_SLOPE * x;
        reinterpret_cast<float4*>(out)[i] = v;
    }
}

// ===========================================================================
// Fallback (tiny ws): verified fp32 pipeline from R2
// ===========================================================================
#define TM 64
#define FS 68
__global__ __launch_bounds__(256) void conv_f32(
    const float* __restrict__ feats, const float* __restrict__ W,
    const int* __restrict__ nbr, const int* __restrict__ mask,
    float* __restrict__ out, float* __restrict__ bsums)
{
    __shared__ float f_s[CIN * FS];
    __shared__ float w_s[CIN * COUT];
    const int t = threadIdx.x;
    const int tx = t & 15, ty = t >> 4;
    const int base = blockIdx.x * TM;
    const int gr = t >> 2, cq = t & 3;
    const int n_g = base + gr;
    float acc[4][4];
#pragma unroll
    for (int i = 0; i < 4; ++i)
#pragma unroll
        for (int j = 0; j < 4; ++j) acc[i][j] = 0.0f;
    for (int k = 0; k < KNBR; ++k) {
        int idx = -1;
        if (n_g < N_VOX) {
            const long off = (long)n_g * KNBR + k;
            if (mask[off] != 0) idx = nbr[off];
        }
        float4 fa = make_float4(0.f, 0.f, 0.f, 0.f);
        float4 fbv = fa;
        if (idx >= 0) {
            const float4* fp = reinterpret_cast<const float4*>(feats + (long)idx * CIN + cq * 8);
            fa = fp[0]; fbv = fp[1];
        }
        const float4* wsrc = reinterpret_cast<const float4*>(W + (long)k * CIN * COUT + t * 8);
        const float4 wa = wsrc[0], wb = wsrc[1];
        __syncthreads();
        const int c0 = cq * 8;
        f_s[(c0 + 0) * FS + gr] = fa.x; f_s[(c0 + 1) * FS + gr] = fa.y;
        f_s[(c0 + 2) * FS + gr] = fa.z; f_s[(c0 + 3) * FS + gr] = fa.w;
        f_s[(c0 + 4) * FS + gr] = fbv.x; f_s[(c0 + 5) * FS + gr] = fbv.y;
        f_s[(c0 + 6) * FS + gr] = fbv.z; f_s[(c0 + 7) * FS + gr] = fbv.w;
        reinterpret_cast<float4*>(w_s + t * 8)[0] = wa;
        reinterpret_cast<float4*>(w_s + t * 8)[1] = wb;
        __syncthreads();
#pragma unroll
        for (int c = 0; c < CIN; ++c) {
            const float4 fv = *reinterpret_cast<const float4*>(&f_s[c * FS + ty * 4]);
            const float4 wv = *reinterpret_cast<const float4*>(&w_s[c * COUT + tx * 4]);
            const float fr[4] = {fv.x, fv.y, fv.z, fv.w};
            const float wr[4] = {wv.x, wv.y, wv.z, wv.w};
#pragma unroll
            for (int i = 0; i < 4; ++i)
#pragma unroll
                for (int j = 0; j < 4; ++j)
                    acc[i][j] = fmaf(fr[i], wr[j], acc[i][j]);
        }
    }
#pragma unroll
    for (int i = 0; i < 4; ++i) {
        const int n = base + ty * 4 + i;
        if (n < N_VOX)
            *reinterpret_cast<float4*>(out + (long)n * COUT + tx * 4) =
                make_float4(acc[i][0], acc[i][1], acc[i][2], acc[i][3]);
    }
    float psum[4], psq[4];
#pragma unroll
    for (int j = 0; j < 4; ++j) {
        psum[j] = acc[0][j] + acc[1][j] + acc[2][j] + acc[3][j];
        psq[j]  = acc[0][j] * acc[0][j] + acc[1][j] * acc[1][j]
                + acc[2][j] * acc[2][j] + acc[3][j] * acc[3][j];
    }
    __syncthreads();
    *reinterpret_cast<float4*>(&f_s[ty * 64 + tx * 4]) = make_float4(psum[0], psum[1], psum[2], psum[3]);
    *reinterpret_cast<float4*>(&w_s[ty * 64 + tx * 4]) = make_float4(psq[0], psq[1], psq[2], psq[3]);
    __syncthreads();
    if (t < COUT) {
        float s = 0.f, qq = 0.f;
#pragma unroll
        for (int g = 0; g < 16; ++g) { s += f_s[g * 64 + t]; qq += w_s[g * 64 + t]; }
        float* dst = bsums + (blockIdx.x & (NBUCKET - 1)) * (2 * COUT);
        atomicAdd(dst + t, s);
        atomicAdd(dst + COUT + t, qq);
    }
}

// ===========================================================================
extern "C" void kernel_launch(void* const* d_in, const int* in_sizes, int n_in,
                              void* d_out, int out_size, void* d_ws, size_t ws_size,
                              hipStream_t stream) {
    const float* feats = (const float*)d_in[0];
    const float* W     = (const float*)d_in[1];
    const float* gamma = (const float*)d_in[2];
    const float* beta  = (const float*)d_in[3];
    const int* nbr     = (const int*)d_in[4];
    const int* mask    = (const int*)d_in[5];
    float* out = (float*)d_out;
    char* ws   = (char*)d_ws;

    const size_t fb_bytes = (size_t)N_VOX * CIN * sizeof(__bf16);       // 9,600,000
    const size_t wp_bytes = (size_t)KNBR * 4 * 64 * 8 * sizeof(__bf16); // 110,592
    const size_t bs_bytes = (size_t)NBUCKET * 2 * COUT * sizeof(float); // 32,768

    if (ws_size >= fb_bytes + wp_bytes + bs_bytes) {
        __bf16* fb   = (__bf16*)ws;
        __bf16* Wp   = (__bf16*)(ws + fb_bytes);
        float* bsums = (float*)(ws + fb_bytes + wp_bytes);
        prep_all<<<NB_FEATS + NB_W + NB_Z, 256, 0, stream>>>(feats, W, fb, Wp, bsums);
        conv_mfma5<<<(N_VOX + VPB - 1) / VPB, 256, 0, stream>>>(fb, Wp, nbr, mask, out, bsums);
        bn_stats_apply<<<APPLY_BLOCKS, 256, 0, stream>>>(out, bsums, gamma, beta);
    } else {
        float* bsums = (float*)ws;
        hipMemsetAsync(bsums, 0, bs_bytes, stream);
        conv_f32<<<(N_VOX + TM - 1) / TM, 256, 0, stream>>>(feats, W, nbr, mask, out, bsums);
        bn_stats_apply<<<APPLY_BLOCKS, 256, 0, stream>>>(out, bsums, gamma, beta);
    }
}